// Round 1
// baseline (270.876 us; speedup 1.0000x reference)
//
#include <hip/hip_runtime.h>
#include <hip/hip_bf16.h>
#include <stdint.h>

// Problem constants (B=8192, I=512, H=1024, D=8)
#define B_N 8192
#define I_N 512
#define H_N 1024

typedef __bf16 bf16x8 __attribute__((ext_vector_type(8)));
typedef float f32x16 __attribute__((ext_vector_type(16)));
typedef unsigned short u16;

__device__ inline void gld_lds16(const void* g, void* l) {
  __builtin_amdgcn_global_load_lds(
      (const __attribute__((address_space(1))) unsigned int*)g,
      (__attribute__((address_space(3))) unsigned int*)l,
      16, 0, 0);
}

__device__ inline u16 f2bf(float f) {
  __hip_bfloat16 h = __float2bfloat16(f);
  return __builtin_bit_cast(u16, h);
}

__device__ inline float bf2f(u16 b) {
  unsigned int u = ((unsigned int)b) << 16;
  return __builtin_bit_cast(float, u);
}

// ---------- f32 -> bf16 conversion, 8 elements/thread ----------
__global__ void cvt_kernel(const float* __restrict__ src, u16* __restrict__ dst, int n) {
  int i = (blockIdx.x * 256 + threadIdx.x) * 8;
  if (i >= n) return;
  float4 a = *(const float4*)(src + i);
  float4 b = *(const float4*)(src + i + 4);
  union { u16 u[8]; float4 v; } pk;
  pk.u[0] = f2bf(a.x); pk.u[1] = f2bf(a.y); pk.u[2] = f2bf(a.z); pk.u[3] = f2bf(a.w);
  pk.u[4] = f2bf(b.x); pk.u[5] = f2bf(b.y); pk.u[6] = f2bf(b.z); pk.u[7] = f2bf(b.w);
  *(float4*)(dst + i) = pk.v;
}

// ---------- hidden-state decay: hdec = exp(-relu(delta @ Wg^T + bg)) * h ----------
__global__ void decay_kernel(const float* __restrict__ h, const float* __restrict__ delta,
                             const float* __restrict__ wg, const float* __restrict__ bg,
                             u16* __restrict__ hdec) {
  int idx = blockIdx.x * 256 + threadIdx.x;   // over B*H
  int b = idx >> 10;        // H_N = 1024
  int j = idx & 1023;
  const float4* d4 = (const float4*)(delta + (size_t)b * 8);
  float4 d0 = d4[0], d1 = d4[1];
  const float4* w4 = (const float4*)(wg + (size_t)j * 8);
  float4 w0 = w4[0], w1 = w4[1];
  float t = d0.x*w0.x + d0.y*w0.y + d0.z*w0.z + d0.w*w0.w
          + d1.x*w1.x + d1.y*w1.y + d1.z*w1.z + d1.w*w1.w + bg[j];
  t = t > 0.0f ? t : 0.0f;
  float gam = __expf(-t);
  hdec[idx] = f2bf(gam * h[idx]);
}

// ---------- fused GRU GEMM: 6 accumulators (r,z,n x ih,hh), epilogue fused ----------
__global__ __launch_bounds__(256, 2) void gru_gemm(
    const u16* __restrict__ xb,    // [B, I] bf16
    const u16* __restrict__ hdec,  // [B, H] bf16 (decayed h)
    const u16* __restrict__ wihb,  // [3H, I] bf16
    const u16* __restrict__ whhb,  // [3H, H] bf16
    const float* __restrict__ bih, // [3H]
    const float* __restrict__ bhh, // [3H]
    float* __restrict__ out)       // [B, H] f32
{
  __shared__ __attribute__((aligned(16))) u16 As[64 * 32];
  __shared__ __attribute__((aligned(16))) u16 Ws[3][64 * 32];

  const int tid  = threadIdx.x;
  const int lane = tid & 63;
  const int wave = tid >> 6;
  const int wm = wave & 1;   // which 32-row half of 64
  const int wn = wave >> 1;  // which 32-col half of 64
  const int m0 = blockIdx.x * 64;   // batch-row base
  const int j0 = blockIdx.y * 64;   // hidden-col base

  f32x16 acc[6];
#pragma unroll
  for (int g = 0; g < 6; ++g)
#pragma unroll
    for (int r = 0; r < 16; ++r) acc[g][r] = 0.0f;

  // staging: 256 threads x 16B = 4KB per tile; LDS dst = base + tid*16B (wave-uniform + lane*16)
  const int srow = tid >> 2;          // 0..63 tile row
  const int sseg = (tid & 3) * 8;     // element offset within 32-elem row
  u16* ldsA  = &As[tid * 8];
  u16* ldsW0 = &Ws[0][tid * 8];
  u16* ldsW1 = &Ws[1][tid * 8];
  u16* ldsW2 = &Ws[2][tid * 8];

  // MFMA fragment addressing: A row = lane&31, k = (lane>>5)*8 + j
  const int arow = wm * 32 + (lane & 31);
  const int nrow = wn * 32 + (lane & 31);
  const int koff = (lane >> 5) * 8;

  // ---- K-loop 1: x @ Wih^T (K = 512) ----
  {
    const u16* aSrc  = xb   + (size_t)(m0 + srow) * I_N + sseg;
    const u16* w0Src = wihb + (size_t)(0 * H_N + j0 + srow) * I_N + sseg;
    const u16* w1Src = wihb + (size_t)(1 * H_N + j0 + srow) * I_N + sseg;
    const u16* w2Src = wihb + (size_t)(2 * H_N + j0 + srow) * I_N + sseg;
    for (int k0 = 0; k0 < I_N; k0 += 32) {
      gld_lds16(aSrc + k0, ldsA);
      gld_lds16(w0Src + k0, ldsW0);
      gld_lds16(w1Src + k0, ldsW1);
      gld_lds16(w2Src + k0, ldsW2);
      __syncthreads();
      bf16x8 a0 = *(const bf16x8*)&As[arow * 32 + koff];
      bf16x8 a1 = *(const bf16x8*)&As[arow * 32 + 16 + koff];
#pragma unroll
      for (int g = 0; g < 3; ++g) {
        bf16x8 w0 = *(const bf16x8*)&Ws[g][nrow * 32 + koff];
        bf16x8 w1 = *(const bf16x8*)&Ws[g][nrow * 32 + 16 + koff];
        acc[g] = __builtin_amdgcn_mfma_f32_32x32x16_bf16(a0, w0, acc[g], 0, 0, 0);
        acc[g] = __builtin_amdgcn_mfma_f32_32x32x16_bf16(a1, w1, acc[g], 0, 0, 0);
      }
      __syncthreads();
    }
  }

  // ---- K-loop 2: hdec @ Whh^T (K = 1024) ----
  {
    const u16* aSrc  = hdec + (size_t)(m0 + srow) * H_N + sseg;
    const u16* w0Src = whhb + (size_t)(0 * H_N + j0 + srow) * H_N + sseg;
    const u16* w1Src = whhb + (size_t)(1 * H_N + j0 + srow) * H_N + sseg;
    const u16* w2Src = whhb + (size_t)(2 * H_N + j0 + srow) * H_N + sseg;
    for (int k0 = 0; k0 < H_N; k0 += 32) {
      gld_lds16(aSrc + k0, ldsA);
      gld_lds16(w0Src + k0, ldsW0);
      gld_lds16(w1Src + k0, ldsW1);
      gld_lds16(w2Src + k0, ldsW2);
      __syncthreads();
      bf16x8 a0 = *(const bf16x8*)&As[arow * 32 + koff];
      bf16x8 a1 = *(const bf16x8*)&As[arow * 32 + 16 + koff];
#pragma unroll
      for (int g = 0; g < 3; ++g) {
        bf16x8 w0 = *(const bf16x8*)&Ws[g][nrow * 32 + koff];
        bf16x8 w1 = *(const bf16x8*)&Ws[g][nrow * 32 + 16 + koff];
        acc[3 + g] = __builtin_amdgcn_mfma_f32_32x32x16_bf16(a0, w0, acc[3 + g], 0, 0, 0);
        acc[3 + g] = __builtin_amdgcn_mfma_f32_32x32x16_bf16(a1, w1, acc[3 + g], 0, 0, 0);
      }
      __syncthreads();
    }
  }

  // ---- epilogue: gates + output, fused ----
  // C/D layout (verified m74/m101): col = lane&31, row = (reg&3) + 8*(reg>>2) + 4*(lane>>5)
  const int col = j0 + wn * 32 + (lane & 31);
  const float b_ir = bih[col];
  const float b_iz = bih[H_N + col];
  const float b_in = bih[2 * H_N + col];
  const float b_hr = bhh[col];
  const float b_hz = bhh[H_N + col];
  const float b_hn = bhh[2 * H_N + col];
  const int rbase = m0 + wm * 32 + 4 * (lane >> 5);
#pragma unroll
  for (int r = 0; r < 16; ++r) {
    int row = rbase + (r & 3) + 8 * (r >> 2);
    float ir = acc[0][r] + b_ir;
    float iz = acc[1][r] + b_iz;
    float in_ = acc[2][r] + b_in;
    float hr = acc[3][r] + b_hr;
    float hz = acc[4][r] + b_hz;
    float hn = acc[5][r] + b_hn;
    float rg = 1.0f / (1.0f + __expf(-(ir + hr)));
    float zg = 1.0f / (1.0f + __expf(-(iz + hz)));
    float s  = in_ + rg * hn;
    float e  = __expf(2.0f * s);
    float ng = (e - 1.0f) / (e + 1.0f);   // tanh(s), stable both tails
    float hv = bf2f(hdec[(size_t)row * H_N + col]);
    out[(size_t)row * H_N + col] = ng + zg * (hv - ng);
  }
}

extern "C" void kernel_launch(void* const* d_in, const int* in_sizes, int n_in,
                              void* d_out, int out_size, void* d_ws, size_t ws_size,
                              hipStream_t stream) {
  const float* x     = (const float*)d_in[0];
  const float* delta = (const float*)d_in[1];
  const float* h     = (const float*)d_in[2];
  const float* wih   = (const float*)d_in[3];
  const float* whh   = (const float*)d_in[4];
  const float* bih   = (const float*)d_in[5];
  const float* bhh   = (const float*)d_in[6];
  const float* wg    = (const float*)d_in[7];
  const float* bg    = (const float*)d_in[8];
  float* out = (float*)d_out;

  char* ws = (char*)d_ws;
  u16* xb   = (u16*)(ws);                 // x bf16:   8192*512*2  =  8,388,608 B
  u16* hdec = (u16*)(ws + 8388608);       // hdec bf16:8192*1024*2 = 16,777,216 B
  u16* wihb = (u16*)(ws + 25165824);      // Wih bf16: 3072*512*2  =  3,145,728 B
  u16* whhb = (u16*)(ws + 28311552);      // Whh bf16: 3072*1024*2 =  6,291,456 B (end 34,603,008)

  cvt_kernel<<<B_N * I_N / 8 / 256, 256, 0, stream>>>(x, xb, B_N * I_N);
  cvt_kernel<<<3 * H_N * I_N / 8 / 256, 256, 0, stream>>>(wih, wihb, 3 * H_N * I_N);
  cvt_kernel<<<3 * H_N * H_N / 8 / 256, 256, 0, stream>>>(whh, whhb, 3 * H_N * H_N);
  decay_kernel<<<B_N * H_N / 256, 256, 0, stream>>>(h, delta, wg, bg, hdec);
  gru_gemm<<<dim3(B_N / 64, H_N / 64), 256, 0, stream>>>(xb, hdec, wihb, whhb, bih, bhh, out);
}

// Round 2
// 230.393 us; speedup vs baseline: 1.1757x; 1.1757x over previous
//
#include <hip/hip_runtime.h>
#include <hip/hip_bf16.h>
#include <stdint.h>

// Problem constants (B=8192, I=512, H=1024, D=8)
#define B_N 8192
#define I_N 512
#define H_N 1024

typedef __bf16 bf16x8 __attribute__((ext_vector_type(8)));
typedef float f32x4 __attribute__((ext_vector_type(4)));
typedef unsigned short u16;
typedef unsigned int u32;

__device__ inline void gld_lds16(const void* g, void* l) {
  __builtin_amdgcn_global_load_lds(
      (const __attribute__((address_space(1))) unsigned int*)g,
      (__attribute__((address_space(3))) unsigned int*)l,
      16, 0, 0);
}

__device__ inline u16 f2bf(float f) {
  __hip_bfloat16 h = __float2bfloat16(f);
  return __builtin_bit_cast(u16, h);
}

__device__ inline float bf2f(u16 b) {
  unsigned int u = ((unsigned int)b) << 16;
  return __builtin_bit_cast(float, u);
}

__device__ inline u32 pack2bf(float lo, float hi) {
  return (u32)f2bf(lo) | ((u32)f2bf(hi) << 16);
}

// ---------- fused f32 -> bf16 conversion for x, Wih, Whh (one launch) ----------
// blocks [0,2048): x (4,194,304 el); [2048,2816): wih (1,572,864); [2816,4352): whh (3,145,728)
__global__ void cvt_all(const float* __restrict__ x, const float* __restrict__ wih,
                        const float* __restrict__ whh,
                        u16* __restrict__ xb, u16* __restrict__ wihb, u16* __restrict__ whhb) {
  int b = blockIdx.x;
  const float* src; u16* dst; int base;
  if (b < 2048)      { src = x;   dst = xb;   base = b; }
  else if (b < 2816) { src = wih; dst = wihb; base = b - 2048; }
  else               { src = whh; dst = whhb; base = b - 2816; }
  int i = (base * 256 + (int)threadIdx.x) * 8;
  float4 a0 = *(const float4*)(src + i);
  float4 a1 = *(const float4*)(src + i + 4);
  union { u16 u[8]; float4 v; } pk;
  pk.u[0] = f2bf(a0.x); pk.u[1] = f2bf(a0.y); pk.u[2] = f2bf(a0.z); pk.u[3] = f2bf(a0.w);
  pk.u[4] = f2bf(a1.x); pk.u[5] = f2bf(a1.y); pk.u[6] = f2bf(a1.z); pk.u[7] = f2bf(a1.w);
  *(float4*)(dst + i) = pk.v;
}

// ---------- hidden-state decay: hdec = exp(-relu(delta @ Wg^T + bg)) * h ----------
__global__ void decay_kernel(const float* __restrict__ h, const float* __restrict__ delta,
                             const float* __restrict__ wg, const float* __restrict__ bg,
                             u16* __restrict__ hdec) {
  int idx = blockIdx.x * 256 + threadIdx.x;   // over B*H
  int b = idx >> 10;        // H_N = 1024
  int j = idx & 1023;
  const float4* d4 = (const float4*)(delta + (size_t)b * 8);
  float4 d0 = d4[0], d1 = d4[1];
  const float4* w4 = (const float4*)(wg + (size_t)j * 8);
  float4 w0 = w4[0], w1 = w4[1];
  float t = d0.x*w0.x + d0.y*w0.y + d0.z*w0.z + d0.w*w0.w
          + d1.x*w1.x + d1.y*w1.y + d1.z*w1.z + d1.w*w1.w + bg[j];
  t = t > 0.0f ? t : 0.0f;
  float gam = __expf(-t);
  hdec[idx] = f2bf(gam * h[idx]);
}

// ---------- fused GRU GEMM ----------
// Block tile: 128 batch rows x 64 hidden cols, BK=64 (2 kb-subtiles of 32).
// 4 waves; wave tile 64 rows x 32 cols. MFMA 16x16x32 (conflict-free 64B-row reads).
// ih-gate accumulators parked as packed bf16 between the two K-loops.
__global__ __launch_bounds__(256, 2) void gru_gemm(
    const u16* __restrict__ xb,    // [B, I] bf16
    const u16* __restrict__ hdec,  // [B, H] bf16 (decayed h)
    const u16* __restrict__ wihb,  // [3H, I] bf16
    const u16* __restrict__ whhb,  // [3H, H] bf16
    const float* __restrict__ bih, // [3H]
    const float* __restrict__ bhh, // [3H]
    float* __restrict__ out)       // [B, H] f32
{
  // kb-chunked layout: each kb-subtile is row-major with 32-elem (64B) rows,
  // so global_load_lds's contiguous-per-wave constraint holds AND fragment
  // reads are bank-conflict-free.
  __shared__ __attribute__((aligned(16))) u16 As[2][128 * 32];     // 16 KB
  __shared__ __attribute__((aligned(16))) u16 Ws[3][2][64 * 32];   // 24 KB

  const int tid  = threadIdx.x;
  const int lane = tid & 63;
  const int wave = tid >> 6;
  const int wm = wave & 1;   // row half (64 rows each)
  const int wn = wave >> 1;  // col half (32 cols each)
  const int m0 = blockIdx.x * 128;
  const int j0 = blockIdx.y * 64;

  const int srow = tid >> 2;        // 0..63 staging row
  const int sk   = (tid & 3) * 8;   // k element offset within 32-elem subrow
  const int frow = lane & 15;       // fragment row/col
  const int fk   = (lane >> 4) * 8; // fragment k offset

  f32x4 acc[3][4][2];
  u32 park[3][4][2][2];

#pragma unroll
  for (int g = 0; g < 3; ++g)
#pragma unroll
    for (int rb = 0; rb < 4; ++rb)
#pragma unroll
      for (int cb = 0; cb < 2; ++cb)
#pragma unroll
        for (int r = 0; r < 4; ++r) acc[g][rb][cb][r] = 0.0f;

#define GEMM_PASS(APTR, WPTR, LD, KTOT)                                         \
  for (int k0 = 0; k0 < (KTOT); k0 += 64) {                                     \
    _Pragma("unroll")                                                           \
    for (int kb = 0; kb < 2; ++kb) {                                            \
      _Pragma("unroll")                                                         \
      for (int o = 0; o < 2; ++o)                                               \
        gld_lds16((APTR) + (size_t)(m0 + o * 64 + srow) * (LD) + k0 + kb * 32 + sk, \
                  &As[kb][o * 2048 + tid * 8]);                                 \
      _Pragma("unroll")                                                         \
      for (int g = 0; g < 3; ++g)                                               \
        gld_lds16((WPTR) + (size_t)(g * H_N + j0 + srow) * (LD) + k0 + kb * 32 + sk, \
                  &Ws[g][kb][tid * 8]);                                         \
    }                                                                           \
    __syncthreads();                                                            \
    _Pragma("unroll")                                                           \
    for (int kb = 0; kb < 2; ++kb) {                                            \
      bf16x8 af[4];                                                             \
      _Pragma("unroll")                                                         \
      for (int rb = 0; rb < 4; ++rb)                                            \
        af[rb] = *(const bf16x8*)&As[kb][(wm * 64 + rb * 16 + frow) * 32 + fk]; \
      _Pragma("unroll")                                                         \
      for (int g = 0; g < 3; ++g) {                                             \
        _Pragma("unroll")                                                       \
        for (int cb = 0; cb < 2; ++cb) {                                        \
          bf16x8 wf = *(const bf16x8*)&Ws[g][kb][(wn * 32 + cb * 16 + frow) * 32 + fk]; \
          _Pragma("unroll")                                                     \
          for (int rb = 0; rb < 4; ++rb)                                        \
            acc[g][rb][cb] = __builtin_amdgcn_mfma_f32_16x16x32_bf16(           \
                af[rb], wf, acc[g][rb][cb], 0, 0, 0);                           \
        }                                                                       \
      }                                                                         \
    }                                                                           \
    __syncthreads();                                                            \
  }

  // ---- K-loop 1: x @ Wih^T (K = 512) ----
  GEMM_PASS(xb, wihb, I_N, I_N)

  // park ih gates as packed bf16 (frees 48 regs), re-zero accs
#pragma unroll
  for (int g = 0; g < 3; ++g)
#pragma unroll
    for (int rb = 0; rb < 4; ++rb)
#pragma unroll
      for (int cb = 0; cb < 2; ++cb) {
        park[g][rb][cb][0] = pack2bf(acc[g][rb][cb][0], acc[g][rb][cb][1]);
        park[g][rb][cb][1] = pack2bf(acc[g][rb][cb][2], acc[g][rb][cb][3]);
#pragma unroll
        for (int r = 0; r < 4; ++r) acc[g][rb][cb][r] = 0.0f;
      }

  // ---- K-loop 2: hdec @ Whh^T (K = 1024) ----
  GEMM_PASS(hdec, whhb, H_N, H_N)

#undef GEMM_PASS

  // ---- epilogue: gates + output ----
  // C/D 16x16: col = lane&15, row = (lane>>4)*4 + reg
#pragma unroll
  for (int cb = 0; cb < 2; ++cb) {
    const int col = j0 + wn * 32 + cb * 16 + frow;
    const float b_ir = bih[col];
    const float b_iz = bih[H_N + col];
    const float b_in = bih[2 * H_N + col];
    const float b_hr = bhh[col];
    const float b_hz = bhh[H_N + col];
    const float b_hn = bhh[2 * H_N + col];
#pragma unroll
    for (int rb = 0; rb < 4; ++rb) {
      const int rbase = m0 + wm * 64 + rb * 16 + (lane >> 4) * 4;
#pragma unroll
      for (int r = 0; r < 4; ++r) {
        const int row = rbase + r;
        const int sh = (r & 1) * 16;
        float ir  = bf2f((u16)(park[0][rb][cb][r >> 1] >> sh)) + b_ir;
        float iz  = bf2f((u16)(park[1][rb][cb][r >> 1] >> sh)) + b_iz;
        float in_ = bf2f((u16)(park[2][rb][cb][r >> 1] >> sh)) + b_in;
        float hr = acc[0][rb][cb][r] + b_hr;
        float hz = acc[1][rb][cb][r] + b_hz;
        float hn = acc[2][rb][cb][r] + b_hn;
        float rg = 1.0f / (1.0f + __expf(-(ir + hr)));
        float zg = 1.0f / (1.0f + __expf(-(iz + hz)));
        float s  = in_ + rg * hn;
        float e  = __expf(2.0f * s);
        float ng = (e - 1.0f) / (e + 1.0f);   // tanh(s), stable both tails
        float hv = bf2f(hdec[(size_t)row * H_N + col]);
        out[(size_t)row * H_N + col] = ng + zg * (hv - ng);
      }
    }
  }
}

extern "C" void kernel_launch(void* const* d_in, const int* in_sizes, int n_in,
                              void* d_out, int out_size, void* d_ws, size_t ws_size,
                              hipStream_t stream) {
  const float* x     = (const float*)d_in[0];
  const float* delta = (const float*)d_in[1];
  const float* h     = (const float*)d_in[2];
  const float* wih   = (const float*)d_in[3];
  const float* whh   = (const float*)d_in[4];
  const float* bih   = (const float*)d_in[5];
  const float* bhh   = (const float*)d_in[6];
  const float* wg    = (const float*)d_in[7];
  const float* bg    = (const float*)d_in[8];
  float* out = (float*)d_out;

  char* ws = (char*)d_ws;
  u16* xb   = (u16*)(ws);                 // x bf16:   8192*512*2  =  8,388,608 B
  u16* hdec = (u16*)(ws + 8388608);       // hdec bf16:8192*1024*2 = 16,777,216 B
  u16* wihb = (u16*)(ws + 25165824);      // Wih bf16: 3072*512*2  =  3,145,728 B
  u16* whhb = (u16*)(ws + 28311552);      // Whh bf16: 3072*1024*2 =  6,291,456 B

  cvt_all<<<4352, 256, 0, stream>>>(x, wih, whh, xb, wihb, whhb);
  decay_kernel<<<B_N * H_N / 256, 256, 0, stream>>>(h, delta, wg, bg, hdec);
  gru_gemm<<<dim3(B_N / 128, H_N / 64), 256, 0, stream>>>(xb, hdec, wihb, whhb, bih, bhh, out);
}